// Round 2
// baseline (952.584 us; speedup 1.0000x reference)
//
#include <hip/hip_runtime.h>
#include <math.h>

#define VOCAB   5000
#define T_CTC   512
#define S_TGT   128
#define BATCH   16
#define NEGV    (-1e30f)
#define ALPHA_W 0.2f
#define CONF    0.9f            // 1 - smoothing
#define OFFV    (0.1f / 4999.0f)
#define RING    16

__device__ __forceinline__ float lae2(float x, float y) {
    float m = fmaxf(x, y);
    return m + __logf(__expf(x - m) + __expf(y - m));
}
__device__ __forceinline__ float lae3(float x, float y, float z) {
    float m = fmaxf(fmaxf(x, y), z);
    return m + __logf(__expf(x - m) + __expf(y - m) + __expf(z - m));
}

__global__ __launch_bounds__(256)
void fused_loss_kernel(const float* __restrict__ att,   // (16,128,5000)
                       const float* __restrict__ ctc,   // (16,512,5000)
                       const int*   __restrict__ tgt,   // (16,128)
                       float*       __restrict__ ws)    // ws[0]=att_sum ws[1]=ctc_sum
{
    if (blockIdx.x < BATCH) {
        // ---- CTC: one batch per block, SINGLE WAVE, barrier-free recursion ----
        // Lane k owns extended states s = 4k..4k+3; lane 63 also owns s=256.
        // Cross-lane dependency per step is exactly one value: prev lane's a3.
        if (threadIdx.x >= 64) return;
        const int b = blockIdx.x;
        const int k = threadIdx.x;
        const float* lp = ctc + (size_t)b * T_CTC * VOCAB;
        const int*   tg = tgt + b * S_TGT;

        const int t1 = tg[2 * k];                      // ext[4k+1]
        const int t3 = tg[2 * k + 1];                  // ext[4k+3]
        const int tprev = (k > 0) ? tg[2 * k - 1] : 0;
        const bool al1 = (k > 0) && (t1 != 0) && (t1 != tprev);
        const bool al3 = (t3 != 0) && (t3 != t1);

        // t=0 init: alpha0[0]=lp[0][blank], alpha0[1]=lp[0][tgt0], rest NEG
        float a0 = (k == 0) ? lp[0]  : NEGV;
        float a1 = (k == 0) ? lp[t1] : NEGV;
        float a2 = NEGV, a3 = NEGV, a4 = NEGV;

        // depth-16 register prefetch ring (no barriers -> loads stay in flight)
        float eB[RING], e1r[RING], e3r[RING];
        #pragma unroll
        for (int i = 0; i < RING; ++i) {
            const float* r = lp + (size_t)(1 + i) * VOCAB;
            eB[i] = r[0]; e1r[i] = r[t1]; e3r[i] = r[t3];
        }

        #pragma unroll 16
        for (int t = 1; t < T_CTC; ++t) {
            const int slot = (t - 1) & (RING - 1);
            float e0  = eB[slot];
            float ee1 = e1r[slot];
            float ee3 = e3r[slot];
            int tp = t + RING; tp = (tp < T_CTC) ? tp : (T_CTC - 1);
            const float* r = lp + (size_t)tp * VOCAB;
            eB[slot] = r[0]; e1r[slot] = r[t1]; e3r[slot] = r[t3];

            float p3 = __shfl_up(a3, 1, 64);           // prev lane's state 4k-1
            if (k == 0) p3 = NEGV;
            float n0 = lae2(a0, p3) + e0;                          // s=4k   (blank)
            float n1 = lae3(a1, a0, al1 ? p3 : NEGV) + ee1;        // s=4k+1
            float n2 = lae2(a2, a1) + e0;                          // s=4k+2 (blank)
            float n3 = lae3(a3, a2, al3 ? a1 : NEGV) + ee3;        // s=4k+3
            float n4 = lae2(a4, a3) + e0;                          // s=256 (lane63)
            a0 = n0; a1 = n1; a2 = n2; a3 = n3; a4 = n4;
        }

        if (k == 63) {
            float ll = lae2(a4, a3);                   // states 256, 255
            float loss_b = -ll;
            if (loss_b > 1e20f) loss_b = 0.0f;         // zero_infinity
            atomicAdd(&ws[1], loss_b);
        }
        return;
    }

    // ---- label-smoothing loss: one block per (b,s) row ----
    const int rr = blockIdx.x - BATCH;                 // 0..2047
    const float* row = att + (size_t)rr * VOCAB;
    const float4* row4 = (const float4*)row;           // 5000/4 = 1250 exact

    float sum = 0.0f;
    for (int i = threadIdx.x; i < VOCAB / 4; i += 256) {
        float4 v = row4[i];
        sum += v.x + v.y + v.z + v.w;
    }
    #pragma unroll
    for (int off = 32; off > 0; off >>= 1)
        sum += __shfl_down(sum, off, 64);

    __shared__ float wsum[4];
    const int wave = threadIdx.x >> 6;
    if ((threadIdx.x & 63) == 0) wsum[wave] = sum;
    __syncthreads();
    if (threadIdx.x == 0) {
        float rs = wsum[0] + wsum[1] + wsum[2] + wsum[3];
        float tl = row[tgt[rr]];
        float per_row = -(CONF * tl + OFFV * (rs - tl));
        atomicAdd(&ws[0], per_row);
    }
}

__global__ void combine_kernel(const float* __restrict__ ws, float* __restrict__ out)
{
    if (threadIdx.x == 0 && blockIdx.x == 0) {
        const float inv = 1.0f / (float)(BATCH * S_TGT);   // both sums / 2048
        out[0] = ALPHA_W * (ws[0] * inv) + (1.0f - ALPHA_W) * (ws[1] * inv);
    }
}

extern "C" void kernel_launch(void* const* d_in, const int* in_sizes, int n_in,
                              void* d_out, int out_size, void* d_ws, size_t ws_size,
                              hipStream_t stream)
{
    const float* att = (const float*)d_in[0];
    const float* ctc = (const float*)d_in[1];
    const int*   tgt = (const int*)d_in[2];
    float* out = (float*)d_out;
    float* ws  = (float*)d_ws;

    hipMemsetAsync(ws, 0, 2 * sizeof(float), stream);
    fused_loss_kernel<<<BATCH + BATCH * S_TGT, 256, 0, stream>>>(att, ctc, tgt, ws);
    combine_kernel<<<1, 64, 0, stream>>>(ws, out);
}

// Round 3
// 357.953 us; speedup vs baseline: 2.6612x; 2.6612x over previous
//
#include <hip/hip_runtime.h>
#include <math.h>

#define VOCAB   5000
#define T_CTC   512
#define S_TGT   128
#define BATCH   16
#define ALPHA_W 0.2f
#define CONF    0.9f            // 1 - smoothing
#define OFFV    (0.1f / 4999.0f)
#define CHUNK   32
#define NCHUNK  16              // chunks cover t = 1..512 (t==512 guarded off)

__global__ __launch_bounds__(512)
void fused_loss_kernel(const float* __restrict__ att,   // (16,128,5000)
                       const float* __restrict__ ctc,   // (16,512,5000)
                       const int*   __restrict__ tgt,   // (16,128)
                       float*       __restrict__ ws)    // ws[0]=att_sum ws[1]=ctc_sum
{
    // emission staging: [buf][step-in-chunk][v], v: 0..127 = targets, 128 = blank.
    // row stride 130 keeps float2 reads at [2k] 8-byte aligned (520 % 8 == 0).
    __shared__ __align__(16) float ebuf[2][CHUNK][130];

    if (blockIdx.x < BATCH) {
        // ================= CTC: one batch per block =================
        const int b    = blockIdx.x;
        const int tid  = threadIdx.x;
        const int wave = tid >> 6;
        const int lane = tid & 63;
        const float* lp = ctc + (size_t)b * T_CTC * VOCAB;
        const int*   tg = tgt + b * S_TGT;

        // producer columns (fixed per lane for the whole kernel)
        const int c1 = tg[lane];
        const int c2 = tg[64 + lane];

        // ---- prologue: ALL 8 waves gather chunk 0 (t = 1..32) ----
        {
            float v1[4], v2[4], vb[4];
            #pragma unroll
            for (int j = 0; j < 4; ++j) {
                const int i = wave + 8 * j;                 // 0..31
                const float* row = lp + (size_t)(1 + i) * VOCAB;
                v1[j] = row[c1]; v2[j] = row[c2]; vb[j] = row[0];
            }
            #pragma unroll
            for (int j = 0; j < 4; ++j) {
                const int i = wave + 8 * j;
                ebuf[0][i][lane]      = v1[j];
                ebuf[0][i][64 + lane] = v2[j];
                if (lane == 0) ebuf[0][i][128] = vb[j];
            }
        }

        // ---- consumer state (wave 0): lane k owns states 4k..4k+3 (+256 on lane 63)
        const int k  = lane;
        const int t1 = tg[2 * k];
        const int t3 = tg[2 * k + 1];
        const int tp = (k > 0) ? tg[2 * k - 1] : 0;
        const double g1 = ((k > 0) && (t1 != 0) && (t1 != tp)) ? 1.0 : 0.0;
        const double g3 = ((t3 != 0) && (t3 != t1)) ? 1.0 : 0.0;

        const float e00 = lp[0];                            // lp[t=0][blank]
        double M  = (double)e00;                            // running log-scale
        double b0 = (k == 0) ? 1.0 : 0.0;                   // beta[4k]
        double b1 = (k == 0) ? (double)__expf(lp[t1] - e00) : 0.0;
        double b2 = 0.0, b3 = 0.0, b4 = 0.0;

        __syncthreads();

        // ---- main loop: wave 0 computes chunk c, waves 1-7 gather chunk c+1 ----
        for (int c = 0; c < NCHUNK; ++c) {
            const int buf = c & 1;
            if (wave == 0) {
                const int tbase = 1 + c * CHUNK;
                #pragma unroll
                for (int i = 0; i < CHUNK; ++i) {
                    if (tbase + i < T_CTC) {
                        const float2 e13 = *reinterpret_cast<const float2*>(&ebuf[buf][i][2 * k]);
                        const float  e0  = ebuf[buf][i][128];
                        const double E1 = (double)__expf(e13.x - e0);
                        const double E3 = (double)__expf(e13.y - e0);
                        double p3 = __shfl_up(b3, 1, 64);
                        p3 = (k == 0) ? 0.0 : p3;
                        const double n0 = b0 + p3;                      // blank
                        const double n1 = (b1 + b0 + g1 * p3) * E1;
                        const double n2 = b2 + b1;                      // blank
                        const double n3 = (b3 + b2 + g3 * b1) * E3;
                        const double n4 = b4 + b3;                      // state 256
                        b0 = n0; b1 = n1; b2 = n2; b3 = n3; b4 = n4;
                        M += (double)e0;
                    }
                }
            } else if (c + 1 < NCHUNK) {
                const int nbuf  = buf ^ 1;
                const int tbase = 1 + (c + 1) * CHUNK;
                float v1[5], v2[5], vb[5];
                #pragma unroll
                for (int j = 0; j < 5; ++j) {
                    const int i = (wave - 1) + 7 * j;       // rows of this wave
                    if (i < CHUNK && tbase + i < T_CTC) {
                        const float* row = lp + (size_t)(tbase + i) * VOCAB;
                        v1[j] = row[c1]; v2[j] = row[c2]; vb[j] = row[0];
                    }
                }
                #pragma unroll
                for (int j = 0; j < 5; ++j) {
                    const int i = (wave - 1) + 7 * j;
                    if (i < CHUNK && tbase + i < T_CTC) {
                        ebuf[nbuf][i][lane]      = v1[j];
                        ebuf[nbuf][i][64 + lane] = v2[j];
                        if (lane == 0) ebuf[nbuf][i][128] = vb[j];
                    }
                }
            }
            __syncthreads();
        }

        if (wave == 0 && k == 63) {
            const double bsum = b3 + b4;                    // states 255, 256
            const double ll   = M + log(bsum);              // bsum==0 -> -inf
            float loss_b = (float)(-ll);
            if (!(loss_b <= 1e20f)) loss_b = 0.0f;          // zero_infinity (inf/NaN -> 0)
            atomicAdd(&ws[1], loss_b);
        }
        return;
    }

    // ================= label-smoothing loss: one block per (b,s) row =================
    const int rr = blockIdx.x - BATCH;                      // 0..2047
    const float* row = att + (size_t)rr * VOCAB;
    const float4* row4 = (const float4*)row;                // 5000/4 = 1250 exact

    float sum = 0.0f;
    for (int i = threadIdx.x; i < VOCAB / 4; i += 512) {
        float4 v = row4[i];
        sum += v.x + v.y + v.z + v.w;
    }
    #pragma unroll
    for (int off = 32; off > 0; off >>= 1)
        sum += __shfl_down(sum, off, 64);

    __shared__ float wsum[8];
    const int wv = threadIdx.x >> 6;
    if ((threadIdx.x & 63) == 0) wsum[wv] = sum;
    __syncthreads();
    if (threadIdx.x == 0) {
        float rs = 0.0f;
        #pragma unroll
        for (int i = 0; i < 8; ++i) rs += wsum[i];
        const float tl = row[tgt[rr]];
        atomicAdd(&ws[0], -(CONF * tl + OFFV * (rs - tl)));
    }
}

__global__ void combine_kernel(const float* __restrict__ ws, float* __restrict__ out)
{
    if (threadIdx.x == 0 && blockIdx.x == 0) {
        const float inv = 1.0f / (float)(BATCH * S_TGT);    // both sums / 2048
        out[0] = ALPHA_W * (ws[0] * inv) + (1.0f - ALPHA_W) * (ws[1] * inv);
    }
}

extern "C" void kernel_launch(void* const* d_in, const int* in_sizes, int n_in,
                              void* d_out, int out_size, void* d_ws, size_t ws_size,
                              hipStream_t stream)
{
    const float* att = (const float*)d_in[0];
    const float* ctc = (const float*)d_in[1];
    const int*   tgt = (const int*)d_in[2];
    float* out = (float*)d_out;
    float* ws  = (float*)d_ws;

    hipMemsetAsync(ws, 0, 2 * sizeof(float), stream);
    // CTC blocks first (long pole), then 2048 label-smoothing rows.
    fused_loss_kernel<<<BATCH + BATCH * S_TGT, 512, 0, stream>>>(att, ctc, tgt, ws);
    combine_kernel<<<1, 64, 0, stream>>>(ws, out);
}

// Round 4
// 295.478 us; speedup vs baseline: 3.2239x; 1.2114x over previous
//
#include <hip/hip_runtime.h>
#include <math.h>

#define VOCAB   5000
#define T_CTC   512
#define S_TGT   128
#define BATCH   16
#define ALPHA_W 0.2f
#define CONF    0.9f            // 1 - smoothing
#define OFFV    (0.1f / 4999.0f)
#define CHUNK   32
#define NCHUNK  16              // chunks cover t = 1..512 (t==512 guarded off)
#define CSTR    132             // compact row stride (floats): 129 used, 16B-aligned
#define WS_OFF  16              // compact buffer starts at ws + 16 floats (64 B)

// ---------------------------------------------------------------------------
// Kernel 1: device-wide gather. compact[b][t][s] = ctc[b][t][ext_col(s)]
//   s in [0,128): column tgt[b][s];  s == 128: blank (col 0). 129..131 unused.
// 4096 blocks x 256 threads: block handles one (b, t-pair).
// ---------------------------------------------------------------------------
__global__ __launch_bounds__(256)
void gather_kernel(const float* __restrict__ ctc,
                   const int*   __restrict__ tgt,
                   float*       __restrict__ ws)
{
    const int b     = blockIdx.x >> 8;          // 16 batches
    const int tpair = blockIdx.x & 255;         // 256 t-pairs
    const int t0    = 2 * tpair;

    __shared__ int tg[S_TGT];
    if (threadIdx.x < S_TGT) tg[threadIdx.x] = tgt[b * S_TGT + threadIdx.x];
    __syncthreads();

    const float* lp   = ctc + (size_t)b * T_CTC * VOCAB;
    float*       cbuf = ws + WS_OFF + ((size_t)b * T_CTC) * CSTR;

    // 2 timesteps x 129 entries = 258 work items over 256 threads
    for (int v = threadIdx.x; v < 258; v += 256) {
        const int tt  = (v < 129) ? 0 : 1;
        const int idx = (v < 129) ? v : v - 129;
        const int col = (idx < 128) ? tg[idx] : 0;
        cbuf[(size_t)(t0 + tt) * CSTR + idx] = lp[(size_t)(t0 + tt) * VOCAB + col];
    }
}

// ---------------------------------------------------------------------------
// Kernel 2: CTC recursion (blocks 0..15) + label-smoothing rows (16..2063)
// ---------------------------------------------------------------------------
__global__ __launch_bounds__(512)
void fused_loss_kernel(const float* __restrict__ att,
                       const int*   __restrict__ tgt,
                       float*       __restrict__ ws)
{
    __shared__ __align__(16) float ebuf[2][CHUNK][CSTR];

    if (blockIdx.x < BATCH) {
        const int b    = blockIdx.x;
        const int tid  = threadIdx.x;
        const int wave = tid >> 6;
        const int lane = tid & 63;
        const int*   tg   = tgt + b * S_TGT;
        const float* cbuf = ws + WS_OFF + ((size_t)b * T_CTC) * CSTR;

        // ---- prologue: all 8 waves copy chunk 0 (t = 1..32), coalesced float4 ----
        {
            const float4* src = (const float4*)(cbuf + (size_t)1 * CSTR);
            float4*       dst = (float4*)&ebuf[0][0][0];
            for (int i = tid; i < CHUNK * (CSTR / 4); i += 512) dst[i] = src[i];
        }

        // ---- consumer constants (wave 0): lane k owns states 4k..4k+3 (+256 on 63)
        const int k  = lane;
        const int t1 = tg[2 * k];
        const int t3 = tg[2 * k + 1];
        const int tp = (k > 0) ? tg[2 * k - 1] : 0;
        const double g1 = ((k > 0) && (t1 != 0) && (t1 != tp)) ? 1.0 : 0.0;
        const double g3 = ((t3 != 0) && (t3 != t1)) ? 1.0 : 0.0;

        const float e00 = cbuf[128];                        // t=0 blank
        double M  = (double)e00;
        double b0 = (k == 0) ? 1.0 : 0.0;
        double b1 = (k == 0) ? (double)__expf(cbuf[0] - e00) : 0.0;  // t=0, tgt[0]
        double b2 = 0.0, b3 = 0.0, b4 = 0.0;

        __syncthreads();

        // ---- main loop: wave 0 computes chunk c, waves 1-7 copy chunk c+1 ----
        for (int c = 0; c < NCHUNK; ++c) {
            const int buf = c & 1;
            if (wave == 0) {
                const int tbase = 1 + c * CHUNK;
                #pragma unroll
                for (int i = 0; i < CHUNK; ++i) {
                    if (tbase + i < T_CTC) {
                        const float2 e13 = *reinterpret_cast<const float2*>(&ebuf[buf][i][2 * k]);
                        const float  e0  = ebuf[buf][i][128];
                        const double E1 = (double)__expf(e13.x - e0);
                        const double E3 = (double)__expf(e13.y - e0);
                        double p3 = __shfl_up(b3, 1, 64);
                        p3 = (k == 0) ? 0.0 : p3;
                        const double n0 = b0 + p3;
                        const double n1 = (b1 + b0 + g1 * p3) * E1;
                        const double n2 = b2 + b1;
                        const double n3 = (b3 + b2 + g3 * b1) * E3;
                        const double n4 = b4 + b3;
                        b0 = n0; b1 = n1; b2 = n2; b3 = n3; b4 = n4;
                        M += (double)e0;
                    }
                }
            } else if (c + 1 < NCHUNK) {
                const int nbuf  = buf ^ 1;
                const int tbase = 1 + (c + 1) * CHUNK;
                const int rows  = min(CHUNK, T_CTC - tbase);        // 32 or 31
                const float4* src = (const float4*)(cbuf + (size_t)tbase * CSTR);
                float4*       dst = (float4*)&ebuf[nbuf][0][0];
                const int n4v = rows * (CSTR / 4);
                for (int i = tid - 64; i < n4v; i += 448) dst[i] = src[i];
            }
            __syncthreads();
        }

        if (wave == 0 && k == 63) {
            const double bsum = b3 + b4;                    // states 255, 256
            const double ll   = M + log(bsum);
            float loss_b = (float)(-ll);
            if (!(loss_b <= 1e20f)) loss_b = 0.0f;          // zero_infinity
            atomicAdd(&ws[1], loss_b);
        }
        return;
    }

    // ---- label-smoothing loss: one block per (b,s) row ----
    const int rr = blockIdx.x - BATCH;                      // 0..2047
    const float* row = att + (size_t)rr * VOCAB;
    const float4* row4 = (const float4*)row;                // 5000/4 = 1250 exact

    float sum = 0.0f;
    for (int i = threadIdx.x; i < VOCAB / 4; i += 512) {
        float4 v = row4[i];
        sum += v.x + v.y + v.z + v.w;
    }
    #pragma unroll
    for (int off = 32; off > 0; off >>= 1)
        sum += __shfl_down(sum, off, 64);

    __shared__ float wsum[8];
    const int wv = threadIdx.x >> 6;
    if ((threadIdx.x & 63) == 0) wsum[wv] = sum;
    __syncthreads();
    if (threadIdx.x == 0) {
        float rs = 0.0f;
        #pragma unroll
        for (int i = 0; i < 8; ++i) rs += wsum[i];
        const float tl = row[tgt[rr]];
        atomicAdd(&ws[0], -(CONF * tl + OFFV * (rs - tl)));
    }
}

__global__ void combine_kernel(const float* __restrict__ ws, float* __restrict__ out)
{
    if (threadIdx.x == 0 && blockIdx.x == 0) {
        const float inv = 1.0f / (float)(BATCH * S_TGT);    // both sums / 2048
        out[0] = ALPHA_W * (ws[0] * inv) + (1.0f - ALPHA_W) * (ws[1] * inv);
    }
}

extern "C" void kernel_launch(void* const* d_in, const int* in_sizes, int n_in,
                              void* d_out, int out_size, void* d_ws, size_t ws_size,
                              hipStream_t stream)
{
    const float* att = (const float*)d_in[0];
    const float* ctc = (const float*)d_in[1];
    const int*   tgt = (const int*)d_in[2];
    float* out = (float*)d_out;
    float* ws  = (float*)d_ws;

    hipMemsetAsync(ws, 0, 2 * sizeof(float), stream);
    gather_kernel<<<BATCH * (T_CTC / 2), 256, 0, stream>>>(ctc, tgt, ws);
    fused_loss_kernel<<<BATCH + BATCH * S_TGT, 512, 0, stream>>>(att, tgt, ws);
    combine_kernel<<<1, 64, 0, stream>>>(ws, out);
}

// Round 5
// 285.567 us; speedup vs baseline: 3.3358x; 1.0347x over previous
//
#include <hip/hip_runtime.h>
#include <math.h>

#define VOCAB   5000
#define T_CTC   512
#define S_TGT   128
#define BATCH   16
#define ALPHA_W 0.2f
#define CONF    0.9f            // 1 - smoothing
#define OFFV    (0.1f / 4999.0f)
#define CHUNK   64
#define NCHUNK  8               // 8*64 steps cover t = 1..512 (t==512 guarded off)
#define CSTR    132             // compact row stride (floats): 129 used, 16B-aligned
#define ATT_N   (BATCH * S_TGT) // 2048 attention rows
#define WS_OFF  4096            // compact buffer starts at ws + 4096 floats (16 KB)
#define GATHER_BLKS (BATCH * (T_CTC / 2))   // 4096

// ---------------------------------------------------------------------------
// Kernel A: device-wide gather of CTC emission columns + attention row loss.
//   blocks [0, 4096):    compact[b][t][s] = ctc[b][t][col(s)], col 128 = blank
//   blocks [4096, 6144): one label-smoothing row each -> ws[rr] partial
// ---------------------------------------------------------------------------
__global__ __launch_bounds__(256)
void gather_att_kernel(const float* __restrict__ ctc,
                       const float* __restrict__ att,
                       const int*   __restrict__ tgt,
                       float*       __restrict__ ws)
{
    if (blockIdx.x < GATHER_BLKS) {
        const int b     = blockIdx.x >> 8;          // 16 batches
        const int tpair = blockIdx.x & 255;         // 256 t-pairs
        const int t0    = 2 * tpair;

        __shared__ int tg[S_TGT];
        if (threadIdx.x < S_TGT) tg[threadIdx.x] = tgt[b * S_TGT + threadIdx.x];
        __syncthreads();

        const float* lp   = ctc + (size_t)b * T_CTC * VOCAB;
        float*       cbuf = ws + WS_OFF + ((size_t)b * T_CTC) * CSTR;

        for (int v = threadIdx.x; v < 258; v += 256) {
            const int tt  = (v < 129) ? 0 : 1;
            const int idx = (v < 129) ? v : v - 129;
            const int col = (idx < 128) ? tg[idx] : 0;
            cbuf[(size_t)(t0 + tt) * CSTR + idx] = lp[(size_t)(t0 + tt) * VOCAB + col];
        }
        return;
    }

    // ---- label-smoothing row ----
    const int rr = blockIdx.x - GATHER_BLKS;        // 0..2047
    const float* row = att + (size_t)rr * VOCAB;
    const float4* row4 = (const float4*)row;        // 1250 float4 exact

    float sum = 0.0f;
    for (int i = threadIdx.x; i < VOCAB / 4; i += 256) {
        float4 v = row4[i];
        sum += v.x + v.y + v.z + v.w;
    }
    #pragma unroll
    for (int off = 32; off > 0; off >>= 1)
        sum += __shfl_down(sum, off, 64);

    __shared__ float wsum[4];
    if ((threadIdx.x & 63) == 0) wsum[threadIdx.x >> 6] = sum;
    __syncthreads();
    if (threadIdx.x == 0) {
        const float rs = wsum[0] + wsum[1] + wsum[2] + wsum[3];
        const float tl = row[tgt[rr]];
        ws[rr] = -(CONF * tl + OFFV * (rs - tl));   // per-row partial, no atomic
    }
}

// ---------------------------------------------------------------------------
// Kernel B: CTC recursion, one batch per block, producer-consumer waves.
// Consumer (wave 0) hoists 16 steps of LDS reads + exps into registers, then
// runs the pure-f64 serial chain out of registers.
// ---------------------------------------------------------------------------
__global__ __launch_bounds__(512)
void ctc_kernel(const int* __restrict__ tgt, float* __restrict__ ws)
{
    __shared__ __align__(16) float ebuf[2][CHUNK][CSTR];   // 2*64*132*4 = 67.6 KB

    const int b    = blockIdx.x;
    const int tid  = threadIdx.x;
    const int wave = tid >> 6;
    const int lane = tid & 63;
    const int*   tg   = tgt + b * S_TGT;
    const float* cbuf = ws + WS_OFF + ((size_t)b * T_CTC) * CSTR;

    // ---- prologue: all 8 waves copy chunk 0 (t = 1..64), coalesced float4 ----
    {
        const float4* src = (const float4*)(cbuf + (size_t)1 * CSTR);
        float4*       dst = (float4*)&ebuf[0][0][0];
        for (int i = tid; i < CHUNK * (CSTR / 4); i += 512) dst[i] = src[i];
    }

    // ---- consumer constants: lane k owns states 4k..4k+3 (+256 on lane 63) ----
    const int k  = lane;
    const int t1 = tg[2 * k];
    const int t3 = tg[2 * k + 1];
    const int tp = (k > 0) ? tg[2 * k - 1] : 0;
    const double g1 = ((k > 0) && (t1 != 0) && (t1 != tp)) ? 1.0 : 0.0;
    const double g3 = ((t3 != 0) && (t3 != t1)) ? 1.0 : 0.0;

    const float e00 = cbuf[128];                    // t=0 blank
    double M  = (double)e00;
    double b0 = (k == 0) ? 1.0 : 0.0;
    double b1 = (k == 0) ? (double)__expf(cbuf[0] - e00) : 0.0;
    double b2 = 0.0, b3 = 0.0, b4 = 0.0;

    __syncthreads();

    for (int c = 0; c < NCHUNK; ++c) {
        const int buf = c & 1;
        if (wave == 0) {
            const int tbase = 1 + c * CHUNK;
            #pragma unroll
            for (int h = 0; h < CHUNK / 16; ++h) {
                // hoist: 16 steps of emissions + exps into registers (independent of chain)
                double X1[16], X3[16];
                float  Z[16];
                #pragma unroll
                for (int i = 0; i < 16; ++i) {
                    const int st = h * 16 + i;
                    const float2 e13 = *reinterpret_cast<const float2*>(&ebuf[buf][st][2 * k]);
                    const float  e0  = ebuf[buf][st][128];
                    X1[i] = (double)__expf(e13.x - e0);
                    X3[i] = (double)__expf(e13.y - e0);
                    Z[i]  = e0;
                }
                // serial chain: pure f64 arithmetic + one shuffle per step
                #pragma unroll
                for (int i = 0; i < 16; ++i) {
                    if (tbase + h * 16 + i < T_CTC) {
                        double p3 = __shfl_up(b3, 1, 64);
                        p3 = (k == 0) ? 0.0 : p3;
                        const double n0 = b0 + p3;
                        const double n1 = (b1 + b0 + g1 * p3) * X1[i];
                        const double n2 = b2 + b1;
                        const double n3 = (b3 + b2 + g3 * b1) * X3[i];
                        const double n4 = b4 + b3;
                        b0 = n0; b1 = n1; b2 = n2; b3 = n3; b4 = n4;
                        M += (double)Z[i];
                    }
                }
            }
        } else if (c + 1 < NCHUNK) {
            const int nbuf  = buf ^ 1;
            const int tbase = 1 + (c + 1) * CHUNK;
            const int rows  = min(CHUNK, T_CTC - tbase);        // 64 (last: 63)
            const float4* src = (const float4*)(cbuf + (size_t)tbase * CSTR);
            float4*       dst = (float4*)&ebuf[nbuf][0][0];
            const int n4v = rows * (CSTR / 4);
            for (int i = tid - 64; i < n4v; i += 448) dst[i] = src[i];
        }
        __syncthreads();
    }

    if (wave == 0 && k == 63) {
        const double bsum = b3 + b4;                // states 255, 256
        const double ll   = M + log(bsum);          // bsum==0 -> -inf
        float loss_b = (float)(-ll);
        if (!(loss_b <= 1e20f)) loss_b = 0.0f;      // zero_infinity (inf/NaN -> 0)
        ws[ATT_N + b] = loss_b;                     // per-batch slot, no atomic
    }
}

// ---------------------------------------------------------------------------
// Kernel C: final reduction of 2048 att partials + 16 ctc losses.
// ---------------------------------------------------------------------------
__global__ __launch_bounds__(256)
void combine_kernel(const float* __restrict__ ws, float* __restrict__ out)
{
    const int tid = threadIdx.x;
    float s_att = 0.0f;
    for (int i = tid; i < ATT_N; i += 256) s_att += ws[i];
    float s_ctc = (tid < BATCH) ? ws[ATT_N + tid] : 0.0f;

    #pragma unroll
    for (int off = 32; off > 0; off >>= 1) {
        s_att += __shfl_down(s_att, off, 64);
        s_ctc += __shfl_down(s_ctc, off, 64);
    }
    __shared__ float wa[4], wc[4];
    if ((tid & 63) == 0) { wa[tid >> 6] = s_att; wc[tid >> 6] = s_ctc; }
    __syncthreads();
    if (tid == 0) {
        const float inv = 1.0f / (float)ATT_N;      // both sums / 2048
        const float a = (wa[0] + wa[1] + wa[2] + wa[3]) * inv;
        const float c = (wc[0] + wc[1] + wc[2] + wc[3]) * inv;
        out[0] = ALPHA_W * a + (1.0f - ALPHA_W) * c;
    }
}

extern "C" void kernel_launch(void* const* d_in, const int* in_sizes, int n_in,
                              void* d_out, int out_size, void* d_ws, size_t ws_size,
                              hipStream_t stream)
{
    const float* att = (const float*)d_in[0];
    const float* ctc = (const float*)d_in[1];
    const int*   tgt = (const int*)d_in[2];
    float* out = (float*)d_out;
    float* ws  = (float*)d_ws;

    gather_att_kernel<<<GATHER_BLKS + ATT_N, 256, 0, stream>>>(ctc, att, tgt, ws);
    ctc_kernel<<<BATCH, 512, 0, stream>>>(tgt, ws);
    combine_kernel<<<1, 256, 0, stream>>>(ws, out);
}